// Round 2
// baseline (309.413 us; speedup 1.0000x reference)
//
#include <hip/hip_runtime.h>
#include <math.h>

#define NS 4
#define HID 512
#define IN_DIM 342
#define OUT_DIM 311
#define BATCH 1024
#define INP 352               // IN_DIM padded to multiple of 32
#define K0 (NS*INP)           // 1408
#define K12 (NS*HID)          // 2048
#define XROW (IN_DIM+1)       // 343

// workspace float offsets
#define OFF_ACOEF 0
#define OFF_X0    (OFF_ACOEF + BATCH*NS)
#define OFF_W0P   (OFF_X0 + BATCH*K0)
#define OFF_H1    (OFF_W0P + HID*K0)
#define OFF_H2    (OFF_H1 + BATCH*HID)
// total = OFF_H2 + BATCH*HID = ~12.9 MB

__global__ void prep_coef(const float* __restrict__ x, float* __restrict__ acoef) {
    int b = blockIdx.x * blockDim.x + threadIdx.x;
    if (b >= BATCH) return;
    float phase = x[b*XROW + IN_DIM];
    float ps = (float)NS * phase;
    float mu = ps - floorf(ps);
    int i1 = ((int)ps) & (NS-1);
    int i0 = (i1+3)&3, i2 = (i1+1)&3, i3 = (i1+2)&3;
    float mu2 = mu*mu, mu3 = mu2*mu;
    float c0 = -0.5f*mu3 +      mu2 - 0.5f*mu;
    float c1 =  1.5f*mu3 - 2.5f*mu2 + 1.0f;
    float c2 = -1.5f*mu3 + 2.0f*mu2 + 0.5f*mu;
    float c3 =  0.5f*mu3 - 0.5f*mu2;
    acoef[b*4+i0] = c0; acoef[b*4+i1] = c1;
    acoef[b*4+i2] = c2; acoef[b*4+i3] = c3;
}

// X0[b][s*INP+i] = a[b,s] * x[b,i], zero-padded i>=IN_DIM
__global__ void prep_x0(const float* __restrict__ x, const float* __restrict__ acoef,
                        float* __restrict__ X0) {
    int b = blockIdx.x;
    for (int k = threadIdx.x; k < K0; k += blockDim.x) {
        int s = k / INP;
        int i = k - s*INP;
        float v = 0.0f;
        if (i < IN_DIM) v = x[b*XROW + i] * acoef[b*4 + s];
        X0[b*K0 + k] = v;
    }
}

// W0p[o][s*INP+i] = W0[s][o][i], zero-padded
__global__ void prep_w0(const float* __restrict__ W0, float* __restrict__ W0p) {
    int o = blockIdx.x;
    for (int k = threadIdx.x; k < K0; k += blockDim.x) {
        int s = k / INP;
        int i = k - s*INP;
        float v = 0.0f;
        if (i < IN_DIM) v = W0[(s*HID + o)*IN_DIM + i];
        W0p[o*K0 + k] = v;
    }
}

#define BM 64
#define BN 32
#define BK 32
#define TM 4
#define TN 2

// C[b,o] = epilogue( sum_k A'[b,k]*B[o,k] + sum_s a[b,s]*biasw[s,o] )
// LAYER 0: A'=X0 (scale pre-folded, physical K0 wide)
// LAYER 1: A'[b,k]=a[b,k>>9]*H1[b,k&511], B=W1[s][o][i]
// LAYER 2: same with W2, no ELU, N=OUT_DIM
template<int LAYER>
__global__ __launch_bounds__(256) void gemm_l(const float* __restrict__ A,
                                              const float* __restrict__ Bsrc,
                                              const float* __restrict__ acoef,
                                              const float* __restrict__ biasw,
                                              float* __restrict__ C) {
    constexpr int K   = (LAYER==0) ? K0 : K12;
    constexpr int lda = (LAYER==0) ? K0 : HID;
    constexpr int N   = (LAYER==2) ? OUT_DIM : HID;
    constexpr int ldc = (LAYER==2) ? OUT_DIM : HID;

    __shared__ float As[BK][BM+4];
    __shared__ float Bs[BK][BN+4];

    const int tid = threadIdx.x;
    const int m0 = blockIdx.y * BM;
    const int n0 = blockIdx.x * BN;
    const int ty = tid >> 4;   // 0..15
    const int tx = tid & 15;   // 0..15

    float acc[TM][TN] = {};

    for (int k0 = 0; k0 < K; k0 += BK) {
        // ---- stage A (BM x BK, float4 chunks) ----
        #pragma unroll
        for (int q = tid; q < (BM*BK/4); q += 256) {
            int row = q >> 3;       // 0..63
            int cq  = q & 7;        // 0..7
            float4 v;
            float sc = 1.0f;
            if (LAYER == 0) {
                v = *(const float4*)(A + (size_t)(m0+row)*lda + k0 + 4*cq);
            } else {
                // virtual k = k0 + 4*cq; slice s = k0>>9 (constant within BK
                // chunk since BK=32 divides 512); physical col = k & 511
                v = *(const float4*)(A + (size_t)(m0+row)*lda + (k0 & 511) + 4*cq);
                sc = acoef[(m0+row)*4 + (k0 >> 9)];
            }
            As[4*cq+0][row] = v.x * sc;
            As[4*cq+1][row] = v.y * sc;
            As[4*cq+2][row] = v.z * sc;
            As[4*cq+3][row] = v.w * sc;
        }
        // ---- stage B (BN x BK, 1 float4 per thread) ----
        {
            int orow = tid >> 3;    // 0..31
            int cq   = tid & 7;     // 0..7
            int o = n0 + orow;
            float4 v = make_float4(0.f,0.f,0.f,0.f);
            if (LAYER != 2 || o < N) {
                const float* src;
                if (LAYER == 0) {
                    src = Bsrc + (size_t)o*K0 + k0 + 4*cq;
                } else {
                    int kk = k0 + 4*cq;
                    int s = kk >> 9;
                    int i = kk & 511;
                    src = Bsrc + (size_t)s*N*HID + (size_t)o*HID + i;
                }
                v = *(const float4*)src;
            }
            Bs[4*cq+0][orow] = v.x;
            Bs[4*cq+1][orow] = v.y;
            Bs[4*cq+2][orow] = v.z;
            Bs[4*cq+3][orow] = v.w;
        }
        __syncthreads();
        // ---- compute ----
        #pragma unroll
        for (int kk = 0; kk < BK; ++kk) {
            float a[TM], bb[TN];
            #pragma unroll
            for (int i=0;i<TM;i++) a[i]  = As[kk][ty*TM+i];
            #pragma unroll
            for (int j=0;j<TN;j++) bb[j] = Bs[kk][tx*TN+j];
            #pragma unroll
            for (int i=0;i<TM;i++)
                #pragma unroll
                for (int j=0;j<TN;j++)
                    acc[i][j] += a[i]*bb[j];
        }
        __syncthreads();
    }

    // ---- epilogue: bias interp (+ELU), store ----
    #pragma unroll
    for (int i=0;i<TM;i++) {
        int row = m0 + ty*TM + i;
        float a0 = acoef[row*4+0], a1 = acoef[row*4+1],
              a2 = acoef[row*4+2], a3 = acoef[row*4+3];
        #pragma unroll
        for (int j=0;j<TN;j++) {
            int col = n0 + tx*TN + j;
            if (LAYER == 2 && col >= N) continue;
            float bias = a0*biasw[0*N+col] + a1*biasw[1*N+col]
                       + a2*biasw[2*N+col] + a3*biasw[3*N+col];
            float v = acc[i][j] + bias;
            if (LAYER < 2) v = (v > 0.f) ? v : expm1f(v);
            C[(size_t)row*ldc + col] = v;
        }
    }
}

extern "C" void kernel_launch(void* const* d_in, const int* in_sizes, int n_in,
                              void* d_out, int out_size, void* d_ws, size_t ws_size,
                              hipStream_t stream) {
    const float* x  = (const float*)d_in[0];
    const float* W0 = (const float*)d_in[1];
    const float* W1 = (const float*)d_in[2];
    const float* W2 = (const float*)d_in[3];
    const float* b0 = (const float*)d_in[4];
    const float* b1 = (const float*)d_in[5];
    const float* b2 = (const float*)d_in[6];
    float* out = (float*)d_out;
    float* ws  = (float*)d_ws;

    float* acoef = ws + OFF_ACOEF;
    float* X0    = ws + OFF_X0;
    float* W0p   = ws + OFF_W0P;
    float* H1    = ws + OFF_H1;
    float* H2    = ws + OFF_H2;

    prep_coef<<<dim3(4), dim3(256), 0, stream>>>(x, acoef);
    prep_w0<<<dim3(HID), dim3(256), 0, stream>>>(W0, W0p);
    prep_x0<<<dim3(BATCH), dim3(256), 0, stream>>>(x, acoef, X0);

    gemm_l<0><<<dim3(HID/BN, BATCH/BM), dim3(256), 0, stream>>>(X0, W0p, acoef, b0, H1);
    gemm_l<1><<<dim3(HID/BN, BATCH/BM), dim3(256), 0, stream>>>(H1, W1, acoef, b1, H2);
    gemm_l<2><<<dim3((OUT_DIM+BN-1)/BN, BATCH/BM), dim3(256), 0, stream>>>(H2, W2, acoef, b2, out);
}

// Round 3
// 92.438 us; speedup vs baseline: 3.3473x; 3.3473x over previous
//
#include <hip/hip_runtime.h>
#include <hip/hip_fp16.h>
#include <math.h>

typedef _Float16 f16x8 __attribute__((ext_vector_type(8)));
typedef float f32x4 __attribute__((ext_vector_type(4)));

#define NS 4
#define HID 512
#define IN_DIM 342
#define OUT_DIM 311
#define BATCH 1024
#define INP 352            // IN_DIM padded to mult of 32
#define K0V (NS*INP)       // 1408
#define K12V (NS*HID)      // 2048
#define XROW (IN_DIM+1)    // 343

// workspace float offsets (total ~11.9 MB, < 12.9 MB proven capacity)
#define OFF_ACOEF 0
#define OFF_X0H   4096                       // 1024*1408 f16 = 720896 fl
#define OFF_W0H   (OFF_X0H + 720896)         // 512*1408 f16  = 360448 fl
#define OFF_W1H   (OFF_W0H + 360448)         // 512*2048 f16  = 524288 fl
#define OFF_W2H   (OFF_W1H + 524288)         // 320*2048 f16  = 327680 fl
#define OFF_H1X   (OFF_W2H + 327680)         // 1024*2048 f16 = 1048576 fl
#define OFF_H2X   OFF_X0H                    // reuses X0h+W0h region (dead after L0)

__global__ void prep_coef(const float* __restrict__ x, float* __restrict__ acoef) {
    int b = blockIdx.x * blockDim.x + threadIdx.x;
    if (b >= BATCH) return;
    float phase = x[b*XROW + IN_DIM];
    float ps = (float)NS * phase;
    float mu = ps - floorf(ps);
    int i1 = ((int)ps) & (NS-1);
    int i0 = (i1+3)&3, i2 = (i1+1)&3, i3 = (i1+2)&3;
    float mu2 = mu*mu, mu3 = mu2*mu;
    acoef[b*4+i0] = -0.5f*mu3 +      mu2 - 0.5f*mu;
    acoef[b*4+i1] =  1.5f*mu3 - 2.5f*mu2 + 1.0f;
    acoef[b*4+i2] = -1.5f*mu3 + 2.0f*mu2 + 0.5f*mu;
    acoef[b*4+i3] =  0.5f*mu3 - 0.5f*mu2;
}

// X0h[b][s*INP+i] = f16( a[b,s] * x[b,i] ), zero pad i>=IN_DIM
__global__ void prep_x0h(const float* __restrict__ x, const float* __restrict__ acoef,
                         __half* __restrict__ X0h) {
    int b = blockIdx.x;
    for (int k = threadIdx.x; k < K0V; k += blockDim.x) {
        int s = k / INP;
        int i = k - s*INP;
        float v = 0.f;
        if (i < IN_DIM) v = x[b*XROW + i] * acoef[b*4 + s];
        X0h[(size_t)b*K0V + k] = __float2half(v);
    }
}

// W0h[o][s*INP+i] = f16(W0[s][o][i]), zero pad
__global__ void prep_w0h(const float* __restrict__ W0, __half* __restrict__ W0h) {
    int o = blockIdx.x;
    for (int k = threadIdx.x; k < K0V; k += blockDim.x) {
        int s = k / INP;
        int i = k - s*INP;
        float v = 0.f;
        if (i < IN_DIM) v = W0[((size_t)s*HID + o)*IN_DIM + i];
        W0h[(size_t)o*K0V + k] = __float2half(v);
    }
}

// W1h[o][s*HID+i] = f16(W1[s][o][i])
__global__ void prep_w1h(const float* __restrict__ W1, __half* __restrict__ W1h) {
    int o = blockIdx.x;
    for (int k = threadIdx.x; k < K12V; k += blockDim.x) {
        int s = k >> 9, i = k & 511;
        W1h[(size_t)o*K12V + k] = __float2half(W1[((size_t)s*HID + o)*HID + i]);
    }
}

// W2h[o][s*HID+i] = f16(W2[s][o][i]), rows 311..319 zero
__global__ void prep_w2h(const float* __restrict__ W2, __half* __restrict__ W2h) {
    int o = blockIdx.x;   // 0..319
    for (int k = threadIdx.x; k < K12V; k += blockDim.x) {
        int s = k >> 9, i = k & 511;
        float v = 0.f;
        if (o < OUT_DIM) v = W2[((size_t)s*OUT_DIM + o)*HID + i];
        W2h[(size_t)o*K12V + k] = __float2half(v);
    }
}

// C[row][col] = sum_k A[row][k]*B[col][k] (+ bias interp, +ELU)
// A prescaled f16 [1024][K]; B f16 [Npad][K].
// LAYER 0/1: outH[row*2048 + s*512 + col] = f16(c_s * ELU(v))
// LAYER 2:   outF[row*311 + col] = v   (col < 311)
template<int LAYER>
__global__ __launch_bounds__(256) void gemm_mfma(
    const __half* __restrict__ A,
    const __half* __restrict__ Bw,
    const float* __restrict__ acoef,
    const float* __restrict__ bias,
    __half* __restrict__ outH,
    float* __restrict__ outF)
{
    constexpr int K = (LAYER==0) ? K0V : K12V;
    constexpr int NB = (LAYER==2) ? OUT_DIM : HID;   // bias stride

    __shared__ __align__(16) char lbuf[16384];       // sA 8KB | sB 8KB
    char* sA = lbuf;
    char* sB = lbuf + 8192;

    const int t    = threadIdx.x;
    const int m0   = blockIdx.y * 64;
    const int n0   = blockIdx.x * 64;
    const int wid  = t >> 6;
    const int lane = t & 63;
    const int wm   = wid >> 1;     // 0..1
    const int wn   = wid & 1;      // 0..1

    // staging: thread t owns tile row sr, 16 f16 starting at kq*16
    const int sr = t >> 2;
    const int kq = t & 3;
    const __half* aBase = A + (size_t)(m0 + sr)*K + kq*16;
    const __half* bBase = Bw + (size_t)(n0 + sr)*K + kq*16;
    const int wb0 = sr*128 + ((kq*32)      ^ ((sr&7)<<4));
    const int wb1 = sr*128 + ((kq*32 + 16) ^ ((sr&7)<<4));

    f32x4 acc[2][2] = {};

    for (int k0 = 0; k0 < K; k0 += 64) {
        uint4 va0 = *(const uint4*)(aBase + k0);
        uint4 va1 = *(const uint4*)(aBase + k0 + 8);
        uint4 vb0 = *(const uint4*)(bBase + k0);
        uint4 vb1 = *(const uint4*)(bBase + k0 + 8);
        __syncthreads();               // prior iter's LDS reads done
        *(uint4*)(sA + wb0) = va0;
        *(uint4*)(sA + wb1) = va1;
        *(uint4*)(sB + wb0) = vb0;
        *(uint4*)(sB + wb1) = vb1;
        __syncthreads();
        #pragma unroll
        for (int kk = 0; kk < 2; ++kk) {
            const int kb = kk*64 + (lane>>4)*16;   // byte off of this lane's 8 k's
            f16x8 af[2], bf[2];
            #pragma unroll
            for (int mi = 0; mi < 2; ++mi) {
                int rr = wm*32 + mi*16 + (lane&15);
                af[mi] = *(const f16x8*)(sA + rr*128 + (kb ^ ((rr&7)<<4)));
            }
            #pragma unroll
            for (int ni = 0; ni < 2; ++ni) {
                int oo = wn*32 + ni*16 + (lane&15);
                bf[ni] = *(const f16x8*)(sB + oo*128 + (kb ^ ((oo&7)<<4)));
            }
            #pragma unroll
            for (int mi = 0; mi < 2; ++mi)
                #pragma unroll
                for (int ni = 0; ni < 2; ++ni)
                    acc[mi][ni] = __builtin_amdgcn_mfma_f32_16x16x32_f16(
                        af[mi], bf[ni], acc[mi][ni], 0, 0, 0);
        }
    }

    // epilogue: D layout col=lane&15, row=(lane>>4)*4+r  [m89-verified]
    #pragma unroll
    for (int mi = 0; mi < 2; ++mi) {
        #pragma unroll
        for (int r = 0; r < 4; ++r) {
            int row = m0 + wm*32 + mi*16 + (lane>>4)*4 + r;
            float c0 = acoef[row*4+0], c1 = acoef[row*4+1],
                  c2 = acoef[row*4+2], c3 = acoef[row*4+3];
            #pragma unroll
            for (int ni = 0; ni < 2; ++ni) {
                int col = n0 + wn*32 + ni*16 + (lane&15);
                float v = acc[mi][ni][r];
                if (LAYER == 2) {
                    if (col < OUT_DIM) {
                        float bi = c0*bias[col] + c1*bias[NB+col]
                                 + c2*bias[2*NB+col] + c3*bias[3*NB+col];
                        outF[(size_t)row*OUT_DIM + col] = v + bi;
                    }
                } else {
                    float bi = c0*bias[col] + c1*bias[NB+col]
                             + c2*bias[2*NB+col] + c3*bias[3*NB+col];
                    v += bi;
                    v = (v > 0.f) ? v : expm1f(v);
                    size_t o = (size_t)row*K12V + col;
                    outH[o          ] = __float2half(c0*v);
                    outH[o +   HID  ] = __float2half(c1*v);
                    outH[o + 2*HID  ] = __float2half(c2*v);
                    outH[o + 3*HID  ] = __float2half(c3*v);
                }
            }
        }
    }
}

extern "C" void kernel_launch(void* const* d_in, const int* in_sizes, int n_in,
                              void* d_out, int out_size, void* d_ws, size_t ws_size,
                              hipStream_t stream) {
    const float* x  = (const float*)d_in[0];
    const float* W0 = (const float*)d_in[1];
    const float* W1 = (const float*)d_in[2];
    const float* W2 = (const float*)d_in[3];
    const float* b0 = (const float*)d_in[4];
    const float* b1 = (const float*)d_in[5];
    const float* b2 = (const float*)d_in[6];
    float* out = (float*)d_out;
    float* ws  = (float*)d_ws;

    float*  acoef = ws + OFF_ACOEF;
    __half* X0h   = (__half*)(ws + OFF_X0H);
    __half* W0h   = (__half*)(ws + OFF_W0H);
    __half* W1h   = (__half*)(ws + OFF_W1H);
    __half* W2h   = (__half*)(ws + OFF_W2H);
    __half* H1x   = (__half*)(ws + OFF_H1X);
    __half* H2x   = (__half*)(ws + OFF_H2X);

    prep_coef<<<dim3(4),    dim3(256), 0, stream>>>(x, acoef);
    prep_x0h <<<dim3(BATCH),dim3(256), 0, stream>>>(x, acoef, X0h);
    prep_w0h <<<dim3(HID),  dim3(256), 0, stream>>>(W0, W0h);
    prep_w1h <<<dim3(HID),  dim3(256), 0, stream>>>(W1, W1h);
    prep_w2h <<<dim3(320),  dim3(256), 0, stream>>>(W2, W2h);

    gemm_mfma<0><<<dim3(HID/64, BATCH/64), dim3(256), 0, stream>>>(
        X0h, W0h, acoef, b0, H1x, nullptr);
    gemm_mfma<1><<<dim3(HID/64, BATCH/64), dim3(256), 0, stream>>>(
        H1x, W1h, acoef, b1, H2x, nullptr);
    gemm_mfma<2><<<dim3(320/64, BATCH/64), dim3(256), 0, stream>>>(
        H2x, W2h, acoef, b2, nullptr, out);
}

// Round 4
// 62.372 us; speedup vs baseline: 4.9608x; 1.4820x over previous
//
#include <hip/hip_runtime.h>
#include <hip/hip_fp16.h>
#include <math.h>

typedef _Float16 f16x8 __attribute__((ext_vector_type(8)));
typedef float f32x4 __attribute__((ext_vector_type(4)));

#define NS 4
#define HID 512
#define IN_DIM 342
#define OUT_DIM 311
#define BATCH 1024
#define INP 352            // IN_DIM padded to mult of 32
#define K0V (NS*INP)       // 1408
#define K12V (NS*HID)      // 2048
#define XROW (IN_DIM+1)    // 343

// workspace float offsets (~11.9 MB total)
#define OFF_ACOEF 0
#define OFF_X0H   4096                       // 1024*1408 f16 = 720896 fl
#define OFF_W0H   (OFF_X0H + 720896)         // 512*1408 f16  = 360448 fl
#define OFF_W1H   (OFF_W0H + 360448)         // 512*2048 f16  = 524288 fl
#define OFF_W2H   (OFF_W1H + 524288)         // 320*2048 f16  = 327680 fl
#define OFF_H1X   (OFF_W2H + 327680)         // 1024*2048 f16 = 1048576 fl
#define OFF_H2X   OFF_X0H                    // X0h+W0h region dead after L0

// ---- one fused prep kernel ----
// blocks [0,512):    W0h row o       (scalar, padded K=1408)
// blocks [512,1024): W1h row o-512   (f16x8 vectorized, K=2048)
// blocks [1024,1344):W2h row o-1024  (f16x8 vectorized, rows>=311 zero)
// blocks [1344,2368):X0h row b + acoef[b]
__global__ __launch_bounds__(256) void prep_all(
    const float* __restrict__ x,
    const float* __restrict__ W0, const float* __restrict__ W1,
    const float* __restrict__ W2,
    float* __restrict__ acoef,
    __half* __restrict__ X0h, __half* __restrict__ W0h,
    __half* __restrict__ W1h, __half* __restrict__ W2h)
{
    const int bid = blockIdx.x;
    const int t = threadIdx.x;
    if (bid < 512) {                       // W0h
        int o = bid;
        for (int k = t; k < K0V; k += 256) {
            int s = k / INP;
            int i = k - s*INP;
            float v = 0.f;
            if (i < IN_DIM) v = W0[((size_t)s*HID + o)*IN_DIM + i];
            W0h[(size_t)o*K0V + k] = __float2half(v);
        }
    } else if (bid < 1024) {               // W1h
        int o = bid - 512;
        int k = t * 8;                      // 256 threads * 8 = 2048
        int s = k >> 9, i = k & 511;
        const float* src = W1 + ((size_t)s*HID + o)*HID + i;
        float4 v0 = *(const float4*)(src);
        float4 v1 = *(const float4*)(src + 4);
        f16x8 h;
        h[0]=(_Float16)v0.x; h[1]=(_Float16)v0.y; h[2]=(_Float16)v0.z; h[3]=(_Float16)v0.w;
        h[4]=(_Float16)v1.x; h[5]=(_Float16)v1.y; h[6]=(_Float16)v1.z; h[7]=(_Float16)v1.w;
        *(f16x8*)(W1h + (size_t)o*K12V + k) = h;
    } else if (bid < 1344) {               // W2h
        int o = bid - 1024;                 // 0..319
        int k = t * 8;
        int s = k >> 9, i = k & 511;
        f16x8 h = {};
        if (o < OUT_DIM) {
            const float* src = W2 + ((size_t)s*OUT_DIM + o)*HID + i;
            float4 v0 = *(const float4*)(src);
            float4 v1 = *(const float4*)(src + 4);
            h[0]=(_Float16)v0.x; h[1]=(_Float16)v0.y; h[2]=(_Float16)v0.z; h[3]=(_Float16)v0.w;
            h[4]=(_Float16)v1.x; h[5]=(_Float16)v1.y; h[6]=(_Float16)v1.z; h[7]=(_Float16)v1.w;
        }
        *(f16x8*)(W2h + (size_t)o*K12V + k) = h;
    } else {                               // X0h + acoef
        int b = bid - 1344;
        float phase = x[(size_t)b*XROW + IN_DIM];
        float ps = (float)NS * phase;
        float mu = ps - floorf(ps);
        int i1 = ((int)ps) & (NS-1);
        float mu2 = mu*mu, mu3 = mu2*mu;
        // basis coefs for relative offsets: rel = (s - i1) & 3
        float c1 =  1.5f*mu3 - 2.5f*mu2 + 1.0f;           // rel 0
        float c2 = -1.5f*mu3 + 2.0f*mu2 + 0.5f*mu;        // rel 1
        float c3 =  0.5f*mu3 - 0.5f*mu2;                  // rel 2
        float c0 = -0.5f*mu3 +      mu2 - 0.5f*mu;        // rel 3
        if (t < 4) {
            int rel = (t - i1) & 3;
            float sel = (rel==0)?c1:(rel==1)?c2:(rel==2)?c3:c0;
            acoef[b*4 + t] = sel;
        }
        for (int k = t; k < K0V; k += 256) {
            int s = k / INP;
            int i = k - s*INP;
            int rel = (s - i1) & 3;
            float sel = (rel==0)?c1:(rel==1)?c2:(rel==2)?c3:c0;
            float v = 0.f;
            if (i < IN_DIM) v = x[(size_t)b*XROW + i] * sel;
            X0h[(size_t)b*K0V + k] = __float2half(v);
        }
    }
}

// ---- MFMA GEMM: C[row][col] = sum_k A[row][k]*B[col][k] + bias interp ----
// BM=32 x BN=64, BK=64; 4 waves: wm=wid>>1 (16-row half), wn=wid&1 (32-col half)
// LDS double buffer (one barrier/iter) + register prefetch of next tile.
// LAYER 0/1: outH[row*2048 + s*512 + col] = f16(c_s * ELU(v))
// LAYER 2:   outF[row*311 + col] = v
template<int LAYER>
__global__ __launch_bounds__(256) void gemm_mfma(
    const __half* __restrict__ A,
    const __half* __restrict__ Bw,
    const float* __restrict__ acoef,
    const float* __restrict__ bias,
    __half* __restrict__ outH,
    float* __restrict__ outF)
{
    constexpr int K  = (LAYER==0) ? K0V : K12V;
    constexpr int NB = (LAYER==2) ? OUT_DIM : HID;     // bias row stride
    constexpr int NITER = K / 64;

    __shared__ __align__(16) char lbuf[2][12288];      // sA 4KB | sB 8KB each

    const int t    = threadIdx.x;
    const int lane = t & 63;
    const int wid  = t >> 6;
    const int wm   = wid >> 1;
    const int wn   = wid & 1;
    const int m0   = blockIdx.y * 32;
    const int n0   = blockIdx.x * 64;

    // staging addresses
    // A: thread t -> row t>>3 (0..31), 8 f16 at chunk (t&7)*8
    const __half* aSrc = A + (size_t)(m0 + (t>>3))*K + (t&7)*8;
    const int aOff = (t>>3)*128 + (((t&7)*16) ^ (((t>>3)&7)<<4));
    // B: thread t -> row t>>2 (0..63), 16 f16 at chunk (t&3)*16
    const __half* bSrc = Bw + (size_t)(n0 + (t>>2))*K + (t&3)*16;
    const int bOff0 = 4096 + (t>>2)*128 + (((t&3)*32)      ^ (((t>>2)&7)<<4));
    const int bOff1 = 4096 + (t>>2)*128 + (((t&3)*32 + 16) ^ (((t>>2)&7)<<4));

    f32x4 acc[2] = {};

    uint4 va  = *(const uint4*)(aSrc);
    uint4 vb0 = *(const uint4*)(bSrc);
    uint4 vb1 = *(const uint4*)(bSrc + 8);
    *(uint4*)(lbuf[0] + aOff)  = va;
    *(uint4*)(lbuf[0] + bOff0) = vb0;
    *(uint4*)(lbuf[0] + bOff1) = vb1;

    for (int it = 0; it < NITER; ++it) {
        __syncthreads();
        if (it + 1 < NITER) {                 // issue next-tile loads early
            va  = *(const uint4*)(aSrc + (it+1)*64);
            vb0 = *(const uint4*)(bSrc + (it+1)*64);
            vb1 = *(const uint4*)(bSrc + (it+1)*64 + 8);
        }
        const char* sA = lbuf[it & 1];
        const char* sB = lbuf[it & 1] + 4096;
        #pragma unroll
        for (int kk = 0; kk < 2; ++kk) {
            const int kb = kk*64 + (lane>>4)*16;
            const int rr = wm*16 + (lane&15);
            f16x8 af = *(const f16x8*)(sA + rr*128 + (kb ^ ((rr&7)<<4)));
            #pragma unroll
            for (int ni = 0; ni < 2; ++ni) {
                const int oo = wn*32 + ni*16 + (lane&15);
                f16x8 bf = *(const f16x8*)(sB + oo*128 + (kb ^ ((oo&7)<<4)));
                acc[ni] = __builtin_amdgcn_mfma_f32_16x16x32_f16(af, bf, acc[ni], 0, 0, 0);
            }
        }
        if (it + 1 < NITER) {                 // write next buffer (waits vmcnt)
            char* d = lbuf[(it+1) & 1];
            *(uint4*)(d + aOff)  = va;
            *(uint4*)(d + bOff0) = vb0;
            *(uint4*)(d + bOff1) = vb1;
        }
    }

    // epilogue: D layout col=lane&15, row=(lane>>4)*4+r
    #pragma unroll
    for (int r = 0; r < 4; ++r) {
        const int row = m0 + wm*16 + (lane>>4)*4 + r;
        const float c0 = acoef[row*4+0], c1 = acoef[row*4+1],
                    c2 = acoef[row*4+2], c3 = acoef[row*4+3];
        #pragma unroll
        for (int ni = 0; ni < 2; ++ni) {
            const int col = n0 + wn*32 + ni*16 + (lane&15);
            float v = acc[ni][r];
            if (LAYER == 2) {
                if (col < OUT_DIM) {
                    float bi = c0*bias[col] + c1*bias[NB+col]
                             + c2*bias[2*NB+col] + c3*bias[3*NB+col];
                    outF[(size_t)row*OUT_DIM + col] = v + bi;
                }
            } else {
                float bi = c0*bias[col] + c1*bias[NB+col]
                         + c2*bias[2*NB+col] + c3*bias[3*NB+col];
                v += bi;
                v = (v > 0.f) ? v : expm1f(v);
                size_t o = (size_t)row*K12V + col;
                outH[o        ] = __float2half(c0*v);
                outH[o +   HID] = __float2half(c1*v);
                outH[o + 2*HID] = __float2half(c2*v);
                outH[o + 3*HID] = __float2half(c3*v);
            }
        }
    }
}

extern "C" void kernel_launch(void* const* d_in, const int* in_sizes, int n_in,
                              void* d_out, int out_size, void* d_ws, size_t ws_size,
                              hipStream_t stream) {
    const float* x  = (const float*)d_in[0];
    const float* W0 = (const float*)d_in[1];
    const float* W1 = (const float*)d_in[2];
    const float* W2 = (const float*)d_in[3];
    const float* b0 = (const float*)d_in[4];
    const float* b1 = (const float*)d_in[5];
    const float* b2 = (const float*)d_in[6];
    float* out = (float*)d_out;
    float* ws  = (float*)d_ws;

    float*  acoef = ws + OFF_ACOEF;
    __half* X0h   = (__half*)(ws + OFF_X0H);
    __half* W0h   = (__half*)(ws + OFF_W0H);
    __half* W1h   = (__half*)(ws + OFF_W1H);
    __half* W2h   = (__half*)(ws + OFF_W2H);
    __half* H1x   = (__half*)(ws + OFF_H1X);
    __half* H2x   = (__half*)(ws + OFF_H2X);

    prep_all<<<dim3(2368), dim3(256), 0, stream>>>(x, W0, W1, W2, acoef,
                                                   X0h, W0h, W1h, W2h);

    gemm_mfma<0><<<dim3(HID/64, BATCH/32), dim3(256), 0, stream>>>(
        X0h, W0h, acoef, b0, H1x, nullptr);
    gemm_mfma<1><<<dim3(HID/64, BATCH/32), dim3(256), 0, stream>>>(
        H1x, W1h, acoef, b1, H2x, nullptr);
    gemm_mfma<2><<<dim3(320/64, BATCH/32), dim3(256), 0, stream>>>(
        H2x, W2h, acoef, b2, nullptr, out);
}